// Round 5
// baseline (212.171 us; speedup 1.0000x reference)
//
#include <hip/hip_runtime.h>
#include <hip/hip_bf16.h>

// ParamTable: idx = base-2 encoding of 16-wide x_pa row (MSB first),
// p = params[idx] (65536 x 2 f32), outputs (p[:,0], p[:,1]) concatenated:
// out[0..B) = col0, out[B..2B) = col1.
//
// Memory-bound: 128 MiB x_pa stream + 16 MiB out stream + 512 KiB table
// (L2-resident). 4 rows/thread for gather-latency ILP; nontemporal on the
// streams so the table stays hot in L2.

typedef int v4i __attribute__((ext_vector_type(4)));

constexpr int ROWS_PER_THREAD = 4;
constexpr int BLOCK = 256;
constexpr int TILE = BLOCK * ROWS_PER_THREAD;  // 1024 rows per block

__device__ __forceinline__ unsigned encode_idx(v4i a0, v4i a1, v4i a2, v4i a3) {
    return ((unsigned)a0.x << 15) | ((unsigned)a0.y << 14) |
           ((unsigned)a0.z << 13) | ((unsigned)a0.w << 12) |
           ((unsigned)a1.x << 11) | ((unsigned)a1.y << 10) |
           ((unsigned)a1.z << 9)  | ((unsigned)a1.w << 8)  |
           ((unsigned)a2.x << 7)  | ((unsigned)a2.y << 6)  |
           ((unsigned)a2.z << 5)  | ((unsigned)a2.w << 4)  |
           ((unsigned)a3.x << 3)  | ((unsigned)a3.y << 2)  |
           ((unsigned)a3.z << 1)  |  (unsigned)a3.w;
}

__global__ __launch_bounds__(BLOCK) void paramtable_gather_kernel(
    const int* __restrict__ x_pa,      // [B,16] values in {0,1}
    const float* __restrict__ params,  // [65536, 2]
    float* __restrict__ out,           // [2*B]
    int B) {
    int base = blockIdx.x * TILE + threadIdx.x;

    unsigned idx[ROWS_PER_THREAD];
    bool     ok[ROWS_PER_THREAD];

    // Phase 1: stream the 4 rows (independent 64B loads -> 4 idx values)
#pragma unroll
    for (int j = 0; j < ROWS_PER_THREAD; ++j) {
        int b = base + j * BLOCK;
        ok[j] = (b < B);
        if (ok[j]) {
            const v4i* row = reinterpret_cast<const v4i*>(x_pa) + (size_t)b * 4;
            v4i a0 = __builtin_nontemporal_load(row + 0);
            v4i a1 = __builtin_nontemporal_load(row + 1);
            v4i a2 = __builtin_nontemporal_load(row + 2);
            v4i a3 = __builtin_nontemporal_load(row + 3);
            idx[j] = encode_idx(a0, a1, a2, a3);
        }
    }

    // Phase 2: 4 independent table gathers in flight, then streamed stores
    float2 p[ROWS_PER_THREAD];
#pragma unroll
    for (int j = 0; j < ROWS_PER_THREAD; ++j) {
        if (ok[j]) p[j] = reinterpret_cast<const float2*>(params)[idx[j]];
    }
#pragma unroll
    for (int j = 0; j < ROWS_PER_THREAD; ++j) {
        if (ok[j]) {
            int b = base + j * BLOCK;
            __builtin_nontemporal_store(p[j].x, out + b);
            __builtin_nontemporal_store(p[j].y, out + B + b);
        }
    }
}

extern "C" void kernel_launch(void* const* d_in, const int* in_sizes, int n_in,
                              void* d_out, int out_size, void* d_ws, size_t ws_size,
                              hipStream_t stream) {
    // setup_inputs order: x [B] (unused), x_pa [B*16], params [65536*2]
    const int*   x_pa   = (const int*)d_in[1];
    const float* params = (const float*)d_in[2];
    float*       out    = (float*)d_out;

    int B = in_sizes[0];  // x has B elements

    int blocks = (B + TILE - 1) / TILE;
    paramtable_gather_kernel<<<blocks, BLOCK, 0, stream>>>(x_pa, params, out, B);
}